// Round 18
// baseline (47.893 us; speedup 1.0000x reference)
//
#include <hip/hip_runtime.h>

#define N_TOK 131072
#define DIM 64
#define K_CODES 1024
#define ALPHA 0.9f
#define ROWS 128                  // tokens per block
#define NBLK (N_TOK / ROWS)       // 1024 blocks = 4/CU, co-resident
#define NCHUNK 16                 // 16 chunks x 64 codes
#define CHUNK_BYTES 8192          // 64 codes * 64 elem * 2B bf16
#define NBUF 4                    // quad-buffer: prefetch distance 3

typedef short bf16x8 __attribute__((ext_vector_type(8)));
typedef float f32x4  __attribute__((ext_vector_type(4)));

__device__ __forceinline__ short f2bf(float f) {
    unsigned u = __builtin_bit_cast(unsigned, f);
    u += 0x7fffu + ((u >> 16) & 1u);
    return (short)(u >> 16);
}
__device__ __forceinline__ unsigned umin2(unsigned a, unsigned b) { return a < b ? a : b; }

// ---------------- prep: Wb = bf16 PRE-SWIZZLED (dest 16B-group gp holds source group gp^(r&7)),
// ---------------- cinitg[k] = -1.5 - 0.5*||w_k||^2  (MFMA C-init; score = -2*acc - 3)
__global__ __launch_bounds__(256) void prep_kernel(const float* __restrict__ W,
                                                   short* __restrict__ Wb,
                                                   float* __restrict__ cinitg) {
    int u = blockIdx.x * 256 + threadIdx.x;      // 0..8191 : one 16B bf16 group each
    int r  = u >> 3;                             // code row 0..1023
    int gp = u & 7;                              // dest group
    int g  = gp ^ (r & 7);                       // source group (XOR swizzle)
    const float4* s = (const float4*)(W + (size_t)r * DIM + g * 8);
    float4 a = s[0], b = s[1];
    bf16x8 v = { f2bf(a.x), f2bf(a.y), f2bf(a.z), f2bf(a.w),
                 f2bf(b.x), f2bf(b.y), f2bf(b.z), f2bf(b.w) };
    *(bf16x8*)(Wb + (size_t)u * 8) = v;

    if (u < K_CODES) {
        const float4* wr = (const float4*)(W + (size_t)u * DIM);
        float sacc = 0.f;
#pragma unroll
        for (int i = 0; i < DIM / 4; ++i) {
            float4 t = wr[i];
            sacc += t.x * t.x + t.y * t.y + t.z * t.z + t.w * t.w;
        }
        cinitg[u] = -1.5f - 0.5f * sacc;
    }
}

__device__ __forceinline__ void stage_chunk(const short* __restrict__ Wb,
                                            unsigned char* wbuf,
                                            int c, int wv, int lane) {
    const unsigned char* src = (const unsigned char*)Wb + (size_t)c * CHUNK_BYTES;
    unsigned char* dst = wbuf + (c & (NBUF - 1)) * CHUNK_BYTES;
#pragma unroll
    for (int i = 0; i < 2; ++i) {
        int off = wv * 2048 + i * 1024;
        __builtin_amdgcn_global_load_lds(
            (const __attribute__((address_space(1))) unsigned*)(src + off + lane * 16),
            (__attribute__((address_space(3))) unsigned*)(dst + off),
            16, 0, 0);
    }
}

// ---------------- main fused kernel (r14 dataflow + counted-vmcnt pipeline, T3/T4) ----------
__global__ __launch_bounds__(256, 2) void vq_kernel(const float* __restrict__ x,
                                                    const float* __restrict__ W,
                                                    const short* __restrict__ Wb,
                                                    const float* __restrict__ cinitg,
                                                    float* __restrict__ out,
                                                    float* __restrict__ blocksum) {
    __shared__ __align__(16) unsigned char wbuf[NBUF * CHUNK_BYTES];  // 32 KB quad-buffer
    __shared__ float    cis[K_CODES];                                 // 4 KB
    __shared__ unsigned red[2 * ROWS];                                // 1 KB
    __shared__ int      jrow[ROWS];
    __shared__ float    wavesum[4];

    const int t        = threadIdx.x;
    const int wv       = t >> 6;
    const int lane     = t & 63;
    const int l15      = t & 15;
    const int lg       = lane >> 4;
    const int rowhalf  = wv >> 1;        // rows  [rowhalf*64, +64)
    const int codehalf = wv & 1;         // codes [codehalf*32, +32) of each 64-chunk
    const int row0     = blockIdx.x * ROWS;
    const int sw       = (l15 & 7) << 4; // XOR swizzle; r&7 == l15&7 for all read rows

    // ---- stage cinit into LDS (4 KB) ----
#pragma unroll
    for (int i = 0; i < K_CODES / 256; ++i) cis[t + i * 256] = cinitg[t + i * 256];

    // ---- prologue: issue chunks 0..2 ----
    stage_chunk(Wb, wbuf, 0, wv, lane);
    stage_chunk(Wb, wbuf, 1, wv, lane);
    stage_chunk(Wb, wbuf, 2, wv, lane);

    // ---- A fragments (this wave's 64 rows) + x^2 partial ----
    bf16x8 afrag[4][2];
    float x2part = 0.f;
#pragma unroll
    for (int rt = 0; rt < 4; ++rt)
#pragma unroll
        for (int ks = 0; ks < 2; ++ks) {
            const float* p = x + (size_t)(row0 + rowhalf * 64 + rt * 16 + l15) * DIM + ks * 32 + lg * 8;
            float4 a0 = *(const float4*)p;
            float4 a1 = *(const float4*)(p + 4);
            x2part += a0.x * a0.x + a0.y * a0.y + a0.z * a0.z + a0.w * a0.w +
                      a1.x * a1.x + a1.y * a1.y + a1.z * a1.z + a1.w * a1.w;
            bf16x8 f = { f2bf(a0.x), f2bf(a0.y), f2bf(a0.z), f2bf(a0.w),
                         f2bf(a1.x), f2bf(a1.y), f2bf(a1.z), f2bf(a1.w) };
            afrag[rt][ks] = f;
        }

    unsigned best[4][4];
#pragma unroll
    for (int rt = 0; rt < 4; ++rt)
#pragma unroll
        for (int j = 0; j < 4; ++j) best[rt][j] = 0xFFFFFFFFu;

    __syncthreads();   // cis ready (also drains prologue DMA; pipeline refills below)

#pragma unroll 1
    for (int c = 0; c < NCHUNK; ++c) {
        // counted wait: chunk c's own DMAs landed; later chunks STAY IN FLIGHT across barrier
        if (c <= NCHUNK - 3)      asm volatile("s_waitcnt vmcnt(4)" ::: "memory");
        else if (c == NCHUNK - 2) asm volatile("s_waitcnt vmcnt(2)" ::: "memory");
        else                      asm volatile("s_waitcnt vmcnt(0)" ::: "memory");
        __builtin_amdgcn_sched_barrier(0);
        __builtin_amdgcn_s_barrier();      // raw barrier: no vmcnt(0) drain
        __builtin_amdgcn_sched_barrier(0);

        // issue chunk c+3 into buffer (c+3)&3 (= (c-1)&3, fully read before this barrier)
        if (c + 3 < NCHUNK) stage_chunk(Wb, wbuf, c + 3, wv, lane);

        const unsigned char* wb = wbuf + (c & (NBUF - 1)) * CHUNK_BYTES;
#pragma unroll
        for (int ct = 0; ct < 2; ++ct) {
            int r = codehalf * 32 + ct * 16 + l15;       // code row within chunk
            const unsigned char* rowp = wb + r * 128;
            bf16x8 b0 = *(const bf16x8*)(rowp + ((lg * 16) ^ sw));
            bf16x8 b1 = *(const bf16x8*)(rowp + ((64 + lg * 16) ^ sw));
            int kidx = c * 64 + r;
            float ci = cis[kidx];                        // broadcast ds_read
#pragma unroll
            for (int rt = 0; rt < 4; ++rt) {
                f32x4 acc = { ci, ci, ci, ci };
                acc = __builtin_amdgcn_mfma_f32_16x16x32_bf16(afrag[rt][0], b0, acc, 0, 0, 0);
                acc = __builtin_amdgcn_mfma_f32_16x16x32_bf16(afrag[rt][1], b1, acc, 0, 0, 0);
                // C layout: col = lane&15 (= kidx), row-in-tile = lg*4 + j.
                // acc = dot - 0.5*w2 - 1.5 in (-2,-1): raw-bit umin = best score; low 10 bits = k
#pragma unroll
                for (int j = 0; j < 4; ++j) {
                    unsigned pk = (__builtin_bit_cast(unsigned, acc[j]) & 0xFFFFFC00u) | (unsigned)kidx;
                    best[rt][j] = umin2(best[rt][j], pk);
                }
            }
        }
        // no trailing barrier: the next iteration's barrier (after its vmcnt wait) provides
        // the read-done guarantee before buffer (c+4)&3 is overwritten
    }

    // ---- cross-lane argmin: butterfly over the 16 l15 lanes (code dim) ----
#pragma unroll
    for (int rt = 0; rt < 4; ++rt)
#pragma unroll
        for (int j = 0; j < 4; ++j) {
            unsigned v = best[rt][j];
            v = umin2(v, (unsigned)__shfl_xor((int)v, 1));
            v = umin2(v, (unsigned)__shfl_xor((int)v, 2));
            v = umin2(v, (unsigned)__shfl_xor((int)v, 4));
            v = umin2(v, (unsigned)__shfl_xor((int)v, 8));
            if (l15 == 0) red[codehalf * ROWS + rowhalf * 64 + rt * 16 + lg * 4 + j] = v;
        }
    __syncthreads();

    float psum = 0.5f * x2part;      // 2 code-half waves duplicated each x row-tile
    if (t < ROWS) {
        unsigned m = umin2(red[t], red[ROWS + t]);
        jrow[t] = (int)(m & 1023u);
        float a = __builtin_bit_cast(float, m & 0xFFFFFC00u);    // acc (quantized)
        psum += fmaf(-2.f, a, -3.0f);                            // s = w2 - 2dot
    }
    __syncthreads();

    // ---- gather W[j] fp32 (L2-hot) -> out: 2 threads/row, 128B each ----
    {
        int r  = t >> 1;
        int cc = t & 1;
        int j  = jrow[r];
        const float4* wr = (const float4*)(W + (size_t)j * DIM);
        float4* od = (float4*)(out + (size_t)(row0 + r) * DIM);
#pragma unroll
        for (int i = 0; i < 4; ++i) od[cc * 4 + i] = wr[cc * 4 + i];
    }

    // ---- block-reduce loss partial ----
#pragma unroll
    for (int off = 32; off; off >>= 1) psum += __shfl_down(psum, off);
    if (lane == 0) wavesum[wv] = psum;
    __syncthreads();
    if (t == 0) blocksum[blockIdx.x] = wavesum[0] + wavesum[1] + wavesum[2] + wavesum[3];
}

// ---------------- deterministic finish ----------------
__global__ __launch_bounds__(256) void finish_kernel(const float* __restrict__ bs,
                                                     float* __restrict__ out) {
    __shared__ float wavesum[4];
    int t = threadIdx.x;
    float s = 0.f;
    for (int i = t; i < NBLK; i += 256) s += bs[i];
#pragma unroll
    for (int off = 32; off; off >>= 1) s += __shfl_down(s, off);
    if ((t & 63) == 0) wavesum[t >> 6] = s;
    __syncthreads();
    if (t == 0)
        out[(size_t)N_TOK * DIM] = (wavesum[0] + wavesum[1] + wavesum[2] + wavesum[3]) *
                                   ((1.0f + ALPHA) / (float)N_TOK);
}

extern "C" void kernel_launch(void* const* d_in, const int* in_sizes, int n_in,
                              void* d_out, int out_size, void* d_ws, size_t ws_size,
                              hipStream_t stream) {
    const float* x = (const float*)d_in[0];
    const float* W = (const float*)d_in[1];
    float* out = (float*)d_out;
    float* ws  = (float*)d_ws;

    float* blocksum = ws;                   // 1024 floats
    float* cinitg   = ws + 2048;            // 1024 floats
    short* Wb       = (short*)(ws + 3072);  // 65536 bf16 = 128 KB (pre-swizzled)

    prep_kernel<<<32, 256, 0, stream>>>(W, Wb, cinitg);
    vq_kernel<<<NBLK, 256, 0, stream>>>(x, W, Wb, cinitg, out, blocksum);
    finish_kernel<<<1, 256, 0, stream>>>(blocksum, out);
}

// Round 19
// 43.627 us; speedup vs baseline: 1.0978x; 1.0978x over previous
//
#include <hip/hip_runtime.h>

#define N_TOK 131072
#define DIM 64
#define K_CODES 1024
#define ALPHA 0.9f
#define ROWS 128                  // tokens per block
#define NBLK (N_TOK / ROWS)       // 1024 blocks
#define NCHUNK 8                  // 8 chunks x 128 codes
#define CHUNK_BYTES 16384         // 128 codes * 64 elem * 2B bf16

typedef short bf16x8 __attribute__((ext_vector_type(8)));
typedef float f32x4  __attribute__((ext_vector_type(4)));

__device__ __forceinline__ short f2bf(float f) {
    unsigned u = __builtin_bit_cast(unsigned, f);
    u += 0x7fffu + ((u >> 16) & 1u);
    return (short)(u >> 16);
}
__device__ __forceinline__ unsigned umin2(unsigned a, unsigned b) { return a < b ? a : b; }

// ---------------- prep: Wb = bf16 PRE-SWIZZLED (dest 16B-group gp holds source group gp^(r&7)),
// ---------------- cinitg[k] = -1.5 - 0.5*||w_k||^2  (MFMA C-init; score = -2*acc - 3)
__global__ __launch_bounds__(256) void prep_kernel(const float* __restrict__ W,
                                                   short* __restrict__ Wb,
                                                   float* __restrict__ cinitg) {
    int u = blockIdx.x * 256 + threadIdx.x;      // 0..8191 : one 16B bf16 group each
    int r  = u >> 3;                             // code row 0..1023
    int gp = u & 7;                              // dest group
    int g  = gp ^ (r & 7);                       // source group (XOR swizzle)
    const float4* s = (const float4*)(W + (size_t)r * DIM + g * 8);
    float4 a = s[0], b = s[1];
    bf16x8 v = { f2bf(a.x), f2bf(a.y), f2bf(a.z), f2bf(a.w),
                 f2bf(b.x), f2bf(b.y), f2bf(b.z), f2bf(b.w) };
    *(bf16x8*)(Wb + (size_t)u * 8) = v;

    if (u < K_CODES) {
        const float4* wr = (const float4*)(W + (size_t)u * DIM);
        float sacc = 0.f;
#pragma unroll
        for (int i = 0; i < DIM / 4; ++i) {
            float4 t = wr[i];
            sacc += t.x * t.x + t.y * t.y + t.z * t.z + t.w * t.w;
        }
        cinitg[u] = -1.5f - 0.5f * sacc;
    }
}

// ---------------- main fused kernel ----------------
__global__ __launch_bounds__(256, 2) void vq_kernel(const float* __restrict__ x,
                                                    const float* __restrict__ W,
                                                    const short* __restrict__ Wb,
                                                    const float* __restrict__ cinitg,
                                                    float* __restrict__ out,
                                                    float* __restrict__ blocksum) {
    __shared__ __align__(16) unsigned char wbuf[2 * CHUNK_BYTES];  // 32 KB dbuf
    __shared__ float    cis[K_CODES];                              // 4 KB
    __shared__ unsigned red[2 * ROWS];                             // 1 KB
    __shared__ int      jrow[ROWS];
    __shared__ float    wavesum[4];

    const int t        = threadIdx.x;
    const int wv       = t >> 6;
    const int lane     = t & 63;
    const int l15      = t & 15;
    const int lg       = lane >> 4;
    const int rowhalf  = wv >> 1;        // rows  [rowhalf*64, +64)
    const int codehalf = wv & 1;         // codes [codehalf*64, +64) of each 128-chunk
    const int row0     = blockIdx.x * ROWS;
    const int sw       = (l15 & 7) << 4; // XOR swizzle; r&7 == l15&7 for all read rows

    // ---- stage cinit into LDS (4 KB) ----
#pragma unroll
    for (int i = 0; i < K_CODES / 256; ++i) cis[t + i * 256] = cinitg[t + i * 256];

    // ---- stage chunk 0 (wave wv covers bytes [wv*4096, +4096)) ----
#pragma unroll
    for (int i = 0; i < 4; ++i) {
        int off = wv * 4096 + i * 1024;
        __builtin_amdgcn_global_load_lds(
            (const __attribute__((address_space(1))) unsigned*)((const unsigned char*)Wb + off + lane * 16),
            (__attribute__((address_space(3))) unsigned*)(wbuf + off),
            16, 0, 0);
    }

    // ---- A fragments (this wave's 64 rows) + x^2 partial ----
    bf16x8 afrag[4][2];
    float x2part = 0.f;
#pragma unroll
    for (int rt = 0; rt < 4; ++rt)
#pragma unroll
        for (int ks = 0; ks < 2; ++ks) {
            const float* p = x + (size_t)(row0 + rowhalf * 64 + rt * 16 + l15) * DIM + ks * 32 + lg * 8;
            float4 a0 = *(const float4*)p;
            float4 a1 = *(const float4*)(p + 4);
            x2part += a0.x * a0.x + a0.y * a0.y + a0.z * a0.z + a0.w * a0.w +
                      a1.x * a1.x + a1.y * a1.y + a1.z * a1.z + a1.w * a1.w;
            bf16x8 f = { f2bf(a0.x), f2bf(a0.y), f2bf(a0.z), f2bf(a0.w),
                         f2bf(a1.x), f2bf(a1.y), f2bf(a1.z), f2bf(a1.w) };
            afrag[rt][ks] = f;
        }

    unsigned best[4][4];
#pragma unroll
    for (int rt = 0; rt < 4; ++rt)
#pragma unroll
        for (int j = 0; j < 4; ++j) best[rt][j] = 0xFFFFFFFFu;

    __syncthreads();   // chunk 0 staged

#pragma unroll 1
    for (int c = 0; c < NCHUNK; ++c) {
        // issue next-chunk DMA; lands during this chunk's compute
        if (c + 1 < NCHUNK) {
#pragma unroll
            for (int i = 0; i < 4; ++i) {
                int off = wv * 4096 + i * 1024;
                __builtin_amdgcn_global_load_lds(
                    (const __attribute__((address_space(1))) unsigned*)
                        ((const unsigned char*)Wb + (size_t)(c + 1) * CHUNK_BYTES + off + lane * 16),
                    (__attribute__((address_space(3))) unsigned*)(wbuf + ((c + 1) & 1) * CHUNK_BYTES + off),
                    16, 0, 0);
            }
        }

        const unsigned char* wb = wbuf + (c & 1) * CHUNK_BYTES;
#pragma unroll
        for (int ct = 0; ct < 4; ++ct) {
            int r = codehalf * 64 + ct * 16 + l15;       // code row within chunk
            const unsigned char* rowp = wb + r * 128;
            bf16x8 b0 = *(const bf16x8*)(rowp + ((lg * 16) ^ sw));
            bf16x8 b1 = *(const bf16x8*)(rowp + ((64 + lg * 16) ^ sw));
            int kidx = c * 128 + r;
            float ci = cis[kidx];                        // broadcast ds_read
#pragma unroll
            for (int rt = 0; rt < 4; ++rt) {
                f32x4 acc = { ci, ci, ci, ci };
                acc = __builtin_amdgcn_mfma_f32_16x16x32_bf16(afrag[rt][0], b0, acc, 0, 0, 0);
                acc = __builtin_amdgcn_mfma_f32_16x16x32_bf16(afrag[rt][1], b1, acc, 0, 0, 0);
                // C layout: col = lane&15 (= kidx), row-in-tile = lg*4 + j.
                // acc = dot - 0.5*w2 - 1.5 in (-2,-1): raw-bit umin = best score; low 10 bits = k
#pragma unroll
                for (int j = 0; j < 4; ++j) {
                    unsigned pk = (__builtin_bit_cast(unsigned, acc[j]) & 0xFFFFFC00u) | (unsigned)kidx;
                    best[rt][j] = umin2(best[rt][j], pk);
                }
            }
        }
        __syncthreads();   // buf reads done; next-chunk DMA long since landed
    }

    // ---- cross-lane argmin: butterfly over the 16 l15 lanes (code dim) ----
#pragma unroll
    for (int rt = 0; rt < 4; ++rt)
#pragma unroll
        for (int j = 0; j < 4; ++j) {
            unsigned v = best[rt][j];
            v = umin2(v, (unsigned)__shfl_xor((int)v, 1));
            v = umin2(v, (unsigned)__shfl_xor((int)v, 2));
            v = umin2(v, (unsigned)__shfl_xor((int)v, 4));
            v = umin2(v, (unsigned)__shfl_xor((int)v, 8));
            if (l15 == 0) red[codehalf * ROWS + rowhalf * 64 + rt * 16 + lg * 4 + j] = v;
        }
    __syncthreads();

    float psum = 0.5f * x2part;      // 2 code-half waves duplicated each x row-tile
    if (t < ROWS) {
        unsigned m = umin2(red[t], red[ROWS + t]);
        jrow[t] = (int)(m & 1023u);
        float a = __builtin_bit_cast(float, m & 0xFFFFFC00u);    // acc (quantized)
        psum += fmaf(-2.f, a, -3.0f);                            // s = w2 - 2dot
    }
    __syncthreads();

    // ---- gather W[j] fp32 (L2-hot) -> out: 2 threads/row, 128B each ----
    {
        int r  = t >> 1;
        int cc = t & 1;
        int j  = jrow[r];
        const float4* wr = (const float4*)(W + (size_t)j * DIM);
        float4* od = (float4*)(out + (size_t)(row0 + r) * DIM);
#pragma unroll
        for (int i = 0; i < 4; ++i) od[cc * 4 + i] = wr[cc * 4 + i];
    }

    // ---- block-reduce loss partial ----
#pragma unroll
    for (int off = 32; off; off >>= 1) psum += __shfl_down(psum, off);
    if (lane == 0) wavesum[wv] = psum;
    __syncthreads();
    if (t == 0) blocksum[blockIdx.x] = wavesum[0] + wavesum[1] + wavesum[2] + wavesum[3];
}

// ---------------- deterministic finish ----------------
__global__ __launch_bounds__(256) void finish_kernel(const float* __restrict__ bs,
                                                     float* __restrict__ out) {
    __shared__ float wavesum[4];
    int t = threadIdx.x;
    float s = 0.f;
    for (int i = t; i < NBLK; i += 256) s += bs[i];
#pragma unroll
    for (int off = 32; off; off >>= 1) s += __shfl_down(s, off);
    if ((t & 63) == 0) wavesum[t >> 6] = s;
    __syncthreads();
    if (t == 0)
        out[(size_t)N_TOK * DIM] = (wavesum[0] + wavesum[1] + wavesum[2] + wavesum[3]) *
                                   ((1.0f + ALPHA) / (float)N_TOK);
}

extern "C" void kernel_launch(void* const* d_in, const int* in_sizes, int n_in,
                              void* d_out, int out_size, void* d_ws, size_t ws_size,
                              hipStream_t stream) {
    const float* x = (const float*)d_in[0];
    const float* W = (const float*)d_in[1];
    float* out = (float*)d_out;
    float* ws  = (float*)d_ws;

    float* blocksum = ws;                   // 1024 floats
    float* cinitg   = ws + 2048;            // 1024 floats
    short* Wb       = (short*)(ws + 3072);  // 65536 bf16 = 128 KB (pre-swizzled)

    prep_kernel<<<32, 256, 0, stream>>>(W, Wb, cinitg);
    vq_kernel<<<NBLK, 256, 0, stream>>>(x, W, Wb, cinitg, out, blocksum);
    finish_kernel<<<1, 256, 0, stream>>>(blocksum, out);
}